// Round 13
// baseline (281.574 us; speedup 1.0000x reference)
//
#include <hip/hip_runtime.h>
#include <hip/hip_fp16.h>
#include <math.h>

// MaxSim contrastive loss, MI355X — gload_lds 3-buffer counted-vmcnt pipeline
// at 2 blocks/CU.
// Round 11 proved the pipeline (correct, FETCH-efficient) but 96KB LDS forced
// 1 block/CU -> latency-starved. Round 13 = round 11 with BN=64: 3 buffers x
// (16KB A + 8KB B) = 72KB <= 80KB -> 2 blocks/CU, 16 waves/CU. Single barrier
// per phase; loads get one full phase of flight via vmcnt(3) (3 DMA ops per
// STAGE — spill-immune ledger, no destination registers). XCD-bijective
// swizzle (4096 = 8*512) keeps tiles L2-local (r11/r12: FETCH 787->328MB).

constexpr int NB = 128;
constexpr int LQ = 256;
constexpr int LK = 512;
constexpr int DD = 1024;

#define TEMP_INV 20.0f
#define EPSN 1e-12f

typedef __fp16 fp16x2 __attribute__((ext_vector_type(2)));   // cvt_pkrtz return
typedef _Float16 f16x8 __attribute__((ext_vector_type(8)));  // MFMA operand
typedef float f32x4 __attribute__((ext_vector_type(4)));

#define BM 128
#define BN 64
#define BK 32
#define NTILES 32   // DD/BK

__device__ __forceinline__ f16x8 cvt8(f32x4 a, f32x4 b) {
  union { f16x8 v; fp16x2 h[4]; } u;
  u.h[0] = __builtin_amdgcn_cvt_pkrtz(a[0], a[1]);
  u.h[1] = __builtin_amdgcn_cvt_pkrtz(a[2], a[3]);
  u.h[2] = __builtin_amdgcn_cvt_pkrtz(b[0], b[1]);
  u.h[3] = __builtin_amdgcn_cvt_pkrtz(b[2], b[3]);
  return u.v;
}

__device__ __forceinline__ void gload16(const float* g, void* l) {
  __builtin_amdgcn_global_load_lds(
      (const __attribute__((address_space(1))) void*)g,
      (__attribute__((address_space(3))) void*)l, 16, 0, 0);
}

#define WVM3  asm volatile("s_waitcnt vmcnt(3)" ::: "memory")
#define WVM0  asm volatile("s_waitcnt vmcnt(0)" ::: "memory")
#define WAITL asm volatile("s_waitcnt lgkmcnt(0)" ::: "memory")
#define SB()  __builtin_amdgcn_sched_barrier(0)
#define BAR() __builtin_amdgcn_s_barrier()

__global__ __launch_bounds__(512, 2) void maxsim_kernel(
    const float* __restrict__ q, const float* __restrict__ pk,
    const float* __restrict__ nk, const int* __restrict__ pmask,
    const int* __restrict__ nmask, float* __restrict__ part) {
  __shared__ float __align__(16) Asb[3][BM * BK];  // 3 x 16 KB
  __shared__ float __align__(16) Bsb[3][BN * BK];  // 3 x  8 KB  (72 KB total)

  // XCD-aware bijective swizzle: 4096 blocks = 8 XCDs x 512
  const int bid = blockIdx.x;
  const int sw = (bid & 7) * 512 + (bid >> 3);
  const int b = sw >> 5;         // batch (32 blocks per batch)
  const int x = sw & 31;
  const int mt = x >> 4;         // 0..1  (q tile, 128 rows)
  const int nt = (x >> 1) & 7;   // 0..7  (key tile, 64 rows)
  const int kt = x & 1;          // 0=pos 1=neg

  const float* kbase = kt ? nk : pk;
  const int* mbase = kt ? nmask : pmask;

  const float* Ag = q + ((size_t)b * LQ + mt * BM) * DD;
  const float* Bg = kbase + ((size_t)b * LK + nt * BN) * DD;

  const int tid = threadIdx.x;
  const int lane = tid & 63;
  const int w = tid >> 6;        // 0..7
  const int wr = w >> 1;         // 0..3 : A rows wr*32 + [0,32)
  const int wc = w & 1;          // 0..1 : B rows wc*32 + [0,32)
  const int frow = lane & 15;
  const int kgrp = lane >> 4;    // 0..3

  // staging: thread t covers 16B chunk (t&7) of LDS row (t>>3); SOURCE chunk
  // pre-XOR-swizzled so the linear LDS dest ends up swizzled (rule #21,
  // verified rounds 8/11).
  const int srow = tid >> 3;     // 0..63
  const int sgrp = tid & 7;
  const int gsrc = sgrp ^ (srow & 7);   // (srow+64)&7 == srow&7

  float ssqA[2] = {0.f, 0.f};    // valid on wc==0 waves
  float ssqB[2] = {0.f, 0.f};    // valid on wr==0 waves
  f32x4 acc[2][2] = {};

  auto STAGE = [&](int sel, int t) {   // exactly 3 vmcnt ops
    const int koff = t * BK;
    gload16(Ag + (size_t)srow * DD + koff + gsrc * 4,
            (char*)&Asb[sel][0] + w * 1024);
    gload16(Ag + (size_t)(srow + 64) * DD + koff + gsrc * 4,
            (char*)&Asb[sel][0] + 8192 + w * 1024);
    gload16(Bg + (size_t)srow * DD + koff + gsrc * 4,
            (char*)&Bsb[sel][0] + w * 1024);
  };

  auto COMPUTE = [&](int sel) {
    f16x8 af[2], bf[2];
    #pragma unroll
    for (int m = 0; m < 2; ++m) {
      const int row = wr * 32 + m * 16 + frow;
      const int swz = row & 7;
      f32x4 x0 = *(const f32x4*)&Asb[sel][row * BK + (((2 * kgrp) ^ swz) << 2)];
      f32x4 x1 = *(const f32x4*)&Asb[sel][row * BK + (((2 * kgrp + 1) ^ swz) << 2)];
      if (wc == 0)
        ssqA[m] += x0[0]*x0[0]+x0[1]*x0[1]+x0[2]*x0[2]+x0[3]*x0[3]
                 + x1[0]*x1[0]+x1[1]*x1[1]+x1[2]*x1[2]+x1[3]*x1[3];
      af[m] = cvt8(x0, x1);
    }
    #pragma unroll
    for (int n = 0; n < 2; ++n) {
      const int row = wc * 32 + n * 16 + frow;
      const int swz = row & 7;
      f32x4 y0 = *(const f32x4*)&Bsb[sel][row * BK + (((2 * kgrp) ^ swz) << 2)];
      f32x4 y1 = *(const f32x4*)&Bsb[sel][row * BK + (((2 * kgrp + 1) ^ swz) << 2)];
      if (wr == 0)
        ssqB[n] += y0[0]*y0[0]+y0[1]*y0[1]+y0[2]*y0[2]+y0[3]*y0[3]
                 + y1[0]*y1[0]+y1[1]*y1[1]+y1[2]*y1[2]+y1[3]*y1[3];
      bf[n] = cvt8(y0, y1);
    }
    #pragma unroll
    for (int m = 0; m < 2; ++m)
      #pragma unroll
      for (int n = 0; n < 2; ++n)
        acc[m][n] = __builtin_amdgcn_mfma_f32_16x16x32_f16(af[m], bf[n], acc[m][n], 0, 0, 0);
  };

  // ---- prologue: S(0), S(1) issued; S(0) landed; barrier ----
  STAGE(0, 0);
  STAGE(1, 1);
  WVM3; SB(); BAR(); SB();

  // ---- steady state (r11-verified schedule), unrolled x3 ----
  // phase p: STAGE(p+2); vmcnt(3) [S(p+1) landed, S(p+2) flying];
  //          COMPUTE(p); lgkmcnt(0); barrier
  for (int p = 0; p < NTILES - 2; p += 3) {
    STAGE(2, p + 2); WVM3; SB(); COMPUTE(0); WAITL; SB(); BAR(); SB();
    STAGE(0, p + 3); WVM3; SB(); COMPUTE(1); WAITL; SB(); BAR(); SB();
    STAGE(1, p + 4); WVM3; SB(); COMPUTE(2); WAITL; SB(); BAR(); SB();
  }
  // tiles 30 (buf0), 31 (buf1)
  WVM0; SB();
  COMPUTE(0);
  WAITL; SB(); BAR(); SB();
  COMPUTE(1);

  // ---- epilogue: norms, column scales, row-max ----
  if (wc == 0) {
    #pragma unroll
    for (int m = 0; m < 2; ++m) {
      ssqA[m] += __shfl_xor(ssqA[m], 16);
      ssqA[m] += __shfl_xor(ssqA[m], 32);
    }
  }
  if (wr == 0) {
    #pragma unroll
    for (int n = 0; n < 2; ++n) {
      ssqB[n] += __shfl_xor(ssqB[n], 16);
      ssqB[n] += __shfl_xor(ssqB[n], 32);
    }
  }

  // aux aliased onto Asb[0]; all DMA drained (WVM0), last compute reads buf1.
  float* const aux = reinterpret_cast<float*>(&Asb[0][0]);
  float* const csc = aux;             // [BN]  (1/|k|)*mask
  float* const invA_s = aux + BN;     // [BM]  1/|q|
  float* const rmax = aux + BN + BM;  // [BM][2]

  if (wc == 0 && lane < 16) {
    #pragma unroll
    for (int m = 0; m < 2; ++m)
      invA_s[wr * 32 + m * 16 + lane] = 1.0f / fmaxf(sqrtf(ssqA[m]), EPSN);
  }
  if (wr == 0 && lane < 16) {
    #pragma unroll
    for (int n = 0; n < 2; ++n) {
      const int row = wc * 32 + n * 16 + lane;
      const int key = nt * BN + row;
      csc[row] = (mbase[(size_t)b * LK + key] ? 1.0f : 0.0f) /
                 fmaxf(sqrtf(ssqB[n]), EPSN);
    }
  }
  __syncthreads();

  float vmax[2][2];
  #pragma unroll
  for (int m = 0; m < 2; ++m)
    #pragma unroll
    for (int r = 0; r < 2; ++r) vmax[m][r] = -INFINITY;
  float vm4[2][4];
  #pragma unroll
  for (int m = 0; m < 2; ++m)
    #pragma unroll
    for (int r = 0; r < 4; ++r) vm4[m][r] = -INFINITY;
  #pragma unroll
  for (int n = 0; n < 2; ++n) {
    const float s = csc[wc * 32 + n * 16 + frow];
    #pragma unroll
    for (int m = 0; m < 2; ++m)
      #pragma unroll
      for (int r = 0; r < 4; ++r)
        vm4[m][r] = fmaxf(vm4[m][r], acc[m][n][r] * s);
  }
  #pragma unroll
  for (int off = 1; off < 16; off <<= 1)
    #pragma unroll
    for (int m = 0; m < 2; ++m)
      #pragma unroll
      for (int r = 0; r < 4; ++r)
        vm4[m][r] = fmaxf(vm4[m][r], __shfl_xor(vm4[m][r], off));
  if ((lane & 15) == 0) {
    #pragma unroll
    for (int m = 0; m < 2; ++m)
      #pragma unroll
      for (int r = 0; r < 4; ++r)
        rmax[(wr * 32 + m * 16 + kgrp * 4 + r) * 2 + wc] = vm4[m][r];
  }
  __syncthreads();
  if (tid < BM) {
    const float v = fmaxf(rmax[tid * 2], rmax[tid * 2 + 1]) * invA_s[tid];
    part[(((size_t)kt * NB + b) * 8 + nt) * LQ + mt * BM + tid] = v;
  }
}

// ---------------- logits + softplus per batch ----------------
__global__ __launch_bounds__(256) void logits_kernel(
    const float* __restrict__ part, const int* __restrict__ qmask,
    float* __restrict__ nll) {
  int b = blockIdx.x;
  int t = threadIdx.x;  // = lq
  float mp = -INFINITY, mn = -INFINITY;
  #pragma unroll
  for (int ntile = 0; ntile < 8; ++ntile) {
    mp = fmaxf(mp, part[(((size_t)0 * NB + b) * 8 + ntile) * LQ + t]);
    mn = fmaxf(mn, part[(((size_t)1 * NB + b) * 8 + ntile) * LQ + t]);
  }
  float qm = qmask[(size_t)b * LQ + t] ? 1.0f : 0.0f;
  float p = mp * qm;  // 1/|q| already folded into part
  float n = mn * qm;
  #pragma unroll
  for (int o = 32; o; o >>= 1) { p += __shfl_down(p, o); n += __shfl_down(n, o); }
  __shared__ float sp[4], sn[4];
  int lane = t & 63, w = t >> 6;
  if (lane == 0) { sp[w] = p; sn[w] = n; }
  __syncthreads();
  if (t == 0) {
    float ps = sp[0] + sp[1] + sp[2] + sp[3];
    float ns = sn[0] + sn[1] + sn[2] + sn[3];
    float z = (ns - ps) * TEMP_INV;
    nll[b] = z > 0.0f ? z + log1pf(expf(-z)) : log1pf(expf(z));
  }
}

__global__ void finalize_kernel(const float* __restrict__ nll, float* __restrict__ out) {
  __shared__ float s[128];
  int t = threadIdx.x;
  s[t] = nll[t];
  __syncthreads();
  #pragma unroll
  for (int o = 64; o; o >>= 1) {
    if (t < o) s[t] += s[t + o];
    __syncthreads();
  }
  if (t == 0) out[0] = s[0] * (1.0f / 128.0f);
}

extern "C" void kernel_launch(void* const* d_in, const int* in_sizes, int n_in,
                              void* d_out, int out_size, void* d_ws, size_t ws_size,
                              hipStream_t stream) {
  const float* q = (const float*)d_in[0];
  const float* pk = (const float*)d_in[1];
  const float* nk = (const float*)d_in[2];
  const int* qm = (const int*)d_in[3];
  const int* pm = (const int*)d_in[4];
  const int* nm = (const int*)d_in[5];

  float* ws = (float*)d_ws;
  float* part = ws;                // 524288 floats: [kt][b][nt(8)][lq]
  float* nll = part + 524288;      // 128 floats

  maxsim_kernel<<<4096, 512, 0, stream>>>(q, pk, nk, pm, nm, part);
  logits_kernel<<<NB, 256, 0, stream>>>(part, qm, nll);
  finalize_kernel<<<1, 128, 0, stream>>>(nll, (float*)d_out);
}

// Round 14
// 183.801 us; speedup vs baseline: 1.5320x; 1.5320x over previous
//
#include <hip/hip_runtime.h>
#include <hip/hip_fp16.h>
#include <math.h>

// MaxSim contrastive loss, MI355X.
// Round-14 = round-12 champion (f16 LDS BK=64 dbuf, XOR-swizzled, fused ssq,
// 512 thr, 2 blocks/CU, XCD-bijective block swizzle; 191us) +
//  (a) fully unrolled K-loop: all 16 phases' global loads become base+13-bit
//      immediate offsets (it*256B <= 3840), deleting per-phase 64-bit address
//      VALU (r12 showed 25% VALUBusy, ~3x the cvt+ssq static estimate) and
//      making buffer selection compile-time;
//  (b) T5 s_setprio(1) around the MFMA cluster — 2 independent blocks/CU is
//      the attn-like regime where setprio paid (+4-7%), not lockstep GEMM.

constexpr int NB = 128;
constexpr int LQ = 256;
constexpr int LK = 512;
constexpr int DD = 1024;

#define TEMP_INV 20.0f
#define EPSN 1e-12f

typedef __fp16 fp16x2 __attribute__((ext_vector_type(2)));   // cvt_pkrtz return
typedef _Float16 f16x8 __attribute__((ext_vector_type(8)));  // MFMA operand
typedef float f32x4 __attribute__((ext_vector_type(4)));

#define BM 128
#define BN 128
#define BK 64
#define KITERS (DD / BK)   // 16

__device__ inline f16x8 cvt8(float4 a, float4 b) {
  union { f16x8 v; fp16x2 h[4]; } u;
  u.h[0] = __builtin_amdgcn_cvt_pkrtz(a.x, a.y);
  u.h[1] = __builtin_amdgcn_cvt_pkrtz(a.z, a.w);
  u.h[2] = __builtin_amdgcn_cvt_pkrtz(b.x, b.y);
  u.h[3] = __builtin_amdgcn_cvt_pkrtz(b.z, b.w);
  return u.v;
}

__global__ __launch_bounds__(512, 4) void maxsim_kernel(
    const float* __restrict__ q, const float* __restrict__ pk,
    const float* __restrict__ nk, const int* __restrict__ pmask,
    const int* __restrict__ nmask, float* __restrict__ part) {
  __shared__ _Float16 __align__(16) As[2][BM * BK];  // 32 KB
  __shared__ _Float16 __align__(16) Bs[2][BN * BK];  // 32 KB

  // XCD-aware bijective swizzle (r11/r12-verified): 2048 blocks = 8 XCDs x 256.
  const int bid = blockIdx.x;
  const int sw = (bid & 7) * 256 + (bid >> 3);
  const int b = sw >> 4;         // batch
  const int x = sw & 15;
  const int mt = x >> 3;         // 0..1  (q tile)
  const int nt = (x >> 1) & 3;   // 0..3  (key tile)
  const int kt = x & 1;          // 0=pos 1=neg

  const float* kbase = kt ? nk : pk;
  const int* mbase = kt ? nmask : pmask;

  const float* Ag = q + ((size_t)b * LQ + mt * BM) * DD;
  const float* Bg = kbase + ((size_t)b * LK + nt * BN) * DD;

  const int tid = threadIdx.x;
  const int lane = tid & 63;
  const int w = tid >> 6;        // 0..7
  const int wr = w >> 1;         // 0..3 : rows wr*32 + [0,32)
  const int wc = w & 1;          // 0..1 : cols wc*64 + [0,64)
  const int frow = lane & 15;
  const int kgrp = lane >> 4;    // 0..3

  // staging map: thread t -> rows (t>>3)+64i (i=0..1), 16B-chunk c = t&7
  const int srow0 = tid >> 3;    // 0..63
  const int sc = tid & 7;        // chunk of 8 cols

  const float* pa[2];
  const float* pb[2];
  #pragma unroll
  for (int i = 0; i < 2; ++i) {
    pa[i] = Ag + (size_t)(srow0 + 64 * i) * DD + sc * 8;
    pb[i] = Bg + (size_t)(srow0 + 64 * i) * DD + sc * 8;
  }

  float ssqA[2] = {0.f, 0.f};
  float ssqB[2] = {0.f, 0.f};
  f32x4 acc[2][4] = {};

  auto LOADS = [&](int it, float4 (&ra)[2][2], float4 (&rb)[2][2]) {
    const int koff = it * BK;    // it compile-time after unroll -> imm offsets
    #pragma unroll
    for (int i = 0; i < 2; ++i) {
      ra[i][0] = *(const float4*)(pa[i] + koff);
      ra[i][1] = *(const float4*)(pa[i] + koff + 4);
      rb[i][0] = *(const float4*)(pb[i] + koff);
      rb[i][1] = *(const float4*)(pb[i] + koff + 4);
    }
  };
  auto STORE = [&](int bsel, float4 (&ra)[2][2], float4 (&rb)[2][2]) {
    #pragma unroll
    for (int i = 0; i < 2; ++i) {
      float4 a0 = ra[i][0], a1 = ra[i][1], b0 = rb[i][0], b1 = rb[i][1];
      ssqA[i] += a0.x * a0.x + a0.y * a0.y + a0.z * a0.z + a0.w * a0.w +
                 a1.x * a1.x + a1.y * a1.y + a1.z * a1.z + a1.w * a1.w;
      ssqB[i] += b0.x * b0.x + b0.y * b0.y + b0.z * b0.z + b0.w * b0.w +
                 b1.x * b1.x + b1.y * b1.y + b1.z * b1.z + b1.w * b1.w;
      const int row = srow0 + 64 * i;
      const int cofs = ((sc ^ (row & 7)) << 3);
      *(f16x8*)&As[bsel][row * BK + cofs] = cvt8(a0, a1);
      *(f16x8*)&Bs[bsel][row * BK + cofs] = cvt8(b0, b1);
    }
  };
  auto COMPUTE = [&](int bsel) {
    __builtin_amdgcn_s_setprio(1);
    #pragma unroll
    for (int ks = 0; ks < 2; ++ks) {
      const int ch = ks * 4 + kgrp;
      f16x8 af[2], bf[4];
      #pragma unroll
      for (int m = 0; m < 2; ++m) {
        const int row = wr * 32 + m * 16 + frow;
        af[m] = *(const f16x8*)&As[bsel][row * BK + ((ch ^ (row & 7)) << 3)];
      }
      #pragma unroll
      for (int n = 0; n < 4; ++n) {
        const int row = wc * 64 + n * 16 + frow;
        bf[n] = *(const f16x8*)&Bs[bsel][row * BK + ((ch ^ (row & 7)) << 3)];
      }
      #pragma unroll
      for (int m = 0; m < 2; ++m)
        #pragma unroll
        for (int n = 0; n < 4; ++n)
          acc[m][n] = __builtin_amdgcn_mfma_f32_16x16x32_f16(af[m], bf[n], acc[m][n], 0, 0, 0);
    }
    __builtin_amdgcn_s_setprio(0);
  };

  {
    float4 ca[2][2], cb[2][2];
    LOADS(0, ca, cb);
    STORE(0, ca, cb);
  }
  __syncthreads();

  #pragma unroll
  for (int it = 0; it < KITERS - 1; ++it) {
    float4 na[2][2], nb[2][2];
    LOADS(it + 1, na, nb);   // issue early; imm-offset addressing after unroll
    __builtin_amdgcn_sched_barrier(0);
    COMPUTE(it & 1);
    STORE((it & 1) ^ 1, na, nb);
    __syncthreads();
  }
  COMPUTE(1);                // tile 15 (buf 1)

  // ---- epilogue: norms, column scales, row-max (verified r6/r12) ----
  #pragma unroll
  for (int off = 1; off < 8; off <<= 1) {
    #pragma unroll
    for (int i = 0; i < 2; ++i) {
      ssqA[i] += __shfl_xor(ssqA[i], off);
      ssqB[i] += __shfl_xor(ssqB[i], off);
    }
  }

  // aux arrays aliased onto As[0]; final COMPUTE read As[1]/Bs[1] only.
  float* const aux = reinterpret_cast<float*>(&As[0][0]);
  float* const cs = aux;              // [BN]  (1/|k|)*mask
  float* const invA_s = aux + BN;     // [BM]  1/|q|
  float* const rmax = aux + BN + BM;  // [BM][2]

  if (sc == 0) {
    #pragma unroll
    for (int i = 0; i < 2; ++i) {
      const int row = srow0 + 64 * i;
      invA_s[row] = 1.0f / fmaxf(sqrtf(ssqA[i]), EPSN);
      const int key = nt * BN + row;
      const float mk = mbase[(size_t)b * LK + key] ? 1.0f : 0.0f;
      cs[row] = mk / fmaxf(sqrtf(ssqB[i]), EPSN);
    }
  }
  __syncthreads();

  float vmax[2][4];
  #pragma unroll
  for (int m = 0; m < 2; ++m)
    #pragma unroll
    for (int r = 0; r < 4; ++r) vmax[m][r] = -INFINITY;
  #pragma unroll
  for (int n = 0; n < 4; ++n) {
    const float s = cs[wc * 64 + n * 16 + frow];
    #pragma unroll
    for (int m = 0; m < 2; ++m)
      #pragma unroll
      for (int r = 0; r < 4; ++r)
        vmax[m][r] = fmaxf(vmax[m][r], acc[m][n][r] * s);
  }
  #pragma unroll
  for (int off = 1; off < 16; off <<= 1)
    #pragma unroll
    for (int m = 0; m < 2; ++m)
      #pragma unroll
      for (int r = 0; r < 4; ++r)
        vmax[m][r] = fmaxf(vmax[m][r], __shfl_xor(vmax[m][r], off));
  if ((lane & 15) == 0) {
    #pragma unroll
    for (int m = 0; m < 2; ++m)
      #pragma unroll
      for (int r = 0; r < 4; ++r)
        rmax[(wr * 32 + m * 16 + kgrp * 4 + r) * 2 + wc] = vmax[m][r];
  }
  __syncthreads();
  if (tid < BM) {
    const float v = fmaxf(rmax[tid * 2], rmax[tid * 2 + 1]) * invA_s[tid];
    part[(((size_t)kt * NB + b) * 4 + nt) * LQ + mt * BM + tid] = v;
  }
}

// ---------------- logits + softplus per batch ----------------
__global__ __launch_bounds__(256) void logits_kernel(
    const float* __restrict__ part, const int* __restrict__ qmask,
    float* __restrict__ nll) {
  int b = blockIdx.x;
  int t = threadIdx.x;  // = lq
  float mp = -INFINITY, mn = -INFINITY;
  #pragma unroll
  for (int ntile = 0; ntile < 4; ++ntile) {
    mp = fmaxf(mp, part[(((size_t)0 * NB + b) * 4 + ntile) * LQ + t]);
    mn = fmaxf(mn, part[(((size_t)1 * NB + b) * 4 + ntile) * LQ + t]);
  }
  float qm = qmask[(size_t)b * LQ + t] ? 1.0f : 0.0f;
  float p = mp * qm;  // 1/|q| already folded into part
  float n = mn * qm;
  #pragma unroll
  for (int o = 32; o; o >>= 1) { p += __shfl_down(p, o); n += __shfl_down(n, o); }
  __shared__ float sp[4], sn[4];
  int lane = t & 63, w = t >> 6;
  if (lane == 0) { sp[w] = p; sn[w] = n; }
  __syncthreads();
  if (t == 0) {
    float ps = sp[0] + sp[1] + sp[2] + sp[3];
    float ns = sn[0] + sn[1] + sn[2] + sn[3];
    float z = (ns - ps) * TEMP_INV;
    nll[b] = z > 0.0f ? z + log1pf(expf(-z)) : log1pf(expf(z));
  }
}

__global__ void finalize_kernel(const float* __restrict__ nll, float* __restrict__ out) {
  __shared__ float s[128];
  int t = threadIdx.x;
  s[t] = nll[t];
  __syncthreads();
  #pragma unroll
  for (int o = 64; o; o >>= 1) {
    if (t < o) s[t] += s[t + o];
    __syncthreads();
  }
  if (t == 0) out[0] = s[0] * (1.0f / 128.0f);
}

extern "C" void kernel_launch(void* const* d_in, const int* in_sizes, int n_in,
                              void* d_out, int out_size, void* d_ws, size_t ws_size,
                              hipStream_t stream) {
  const float* q = (const float*)d_in[0];
  const float* pk = (const float*)d_in[1];
  const float* nk = (const float*)d_in[2];
  const int* qm = (const int*)d_in[3];
  const int* pm = (const int*)d_in[4];
  const int* nm = (const int*)d_in[5];

  float* ws = (float*)d_ws;
  float* part = ws;                // 262144 floats: [kt][b][nt][lq]
  float* nll = part + 262144;      // 128 floats

  maxsim_kernel<<<2048, 512, 0, stream>>>(q, pk, nk, pm, nm, part);
  logits_kernel<<<NB, 256, 0, stream>>>(part, qm, nll);
  finalize_kernel<<<1, 128, 0, stream>>>(nll, (float*)d_out);
}

// Round 15
// 180.513 us; speedup vs baseline: 1.5599x; 1.0182x over previous
//
#include <hip/hip_runtime.h>
#include <hip/hip_fp16.h>
#include <math.h>

// MaxSim contrastive loss, MI355X.
// Round-15 = round-14 champion with BK=32 and 32KB LDS -> 4 blocks/CU.
// r14 diagnosis: all pipes <40%, serial per-phase chain with only 2-deep
// block overlap. BK=32 halves the f16 buffers (2x8KB A + 2x8KB B = 32KB),
// quadrupling resident blocks (needs VGPR<=64 — r14 compiled at exactly 64
// with MORE staged regs). 32 shorter phases, 4-deep interleave hides each
// phase's load/store/barrier chain. LDS layout: merged-row [64][8 slots]
// (two K=32 rows per 128B line), slot = (ch | (row&1)<<2) ^ (line&7):
// conflict-free reads, 2-way (free) writes. Grid swizzle, fused ssq,
// epilogue, setprio, full unroll (imm offsets <=3968B) all from r14.

constexpr int NB = 128;
constexpr int LQ = 256;
constexpr int LK = 512;
constexpr int DD = 1024;

#define TEMP_INV 20.0f
#define EPSN 1e-12f

typedef __fp16 fp16x2 __attribute__((ext_vector_type(2)));   // cvt_pkrtz return
typedef _Float16 f16x8 __attribute__((ext_vector_type(8)));  // MFMA operand
typedef float f32x4 __attribute__((ext_vector_type(4)));

#define BM 128
#define BN 128
#define BK 32
#define KITERS (DD / BK)   // 32

__device__ inline f16x8 cvt8(float4 a, float4 b) {
  union { f16x8 v; fp16x2 h[4]; } u;
  u.h[0] = __builtin_amdgcn_cvt_pkrtz(a.x, a.y);
  u.h[1] = __builtin_amdgcn_cvt_pkrtz(a.z, a.w);
  u.h[2] = __builtin_amdgcn_cvt_pkrtz(b.x, b.y);
  u.h[3] = __builtin_amdgcn_cvt_pkrtz(b.z, b.w);
  return u.v;
}

// merged-row LDS index (in f16 units): two K=32 rows per 128B line.
// row 0..127, ch 0..3 (8-f16 chunk of the row's 32 K-cols).
__device__ __forceinline__ int lidx(int row, int ch) {
  const int line = row >> 1;
  const int slot = ((ch | ((row & 1) << 2)) ^ (line & 7));
  return line * 64 + slot * 8;
}

__global__ __launch_bounds__(512, 4) void maxsim_kernel(
    const float* __restrict__ q, const float* __restrict__ pk,
    const float* __restrict__ nk, const int* __restrict__ pmask,
    const int* __restrict__ nmask, float* __restrict__ part) {
  __shared__ _Float16 __align__(16) As[2][BM * BK];  // 2 x 8 KB
  __shared__ _Float16 __align__(16) Bs[2][BN * BK];  // 2 x 8 KB  (32 KB total)

  // XCD-aware bijective swizzle (r11/r12-verified): 2048 = 8 XCDs x 256.
  const int bid = blockIdx.x;
  const int sw = (bid & 7) * 256 + (bid >> 3);
  const int b = sw >> 4;         // batch
  const int x = sw & 15;
  const int mt = x >> 3;         // 0..1  (q tile)
  const int nt = (x >> 1) & 3;   // 0..3  (key tile)
  const int kt = x & 1;          // 0=pos 1=neg

  const float* kbase = kt ? nk : pk;
  const int* mbase = kt ? nmask : pmask;

  const float* Ag = q + ((size_t)b * LQ + mt * BM) * DD;
  const float* Bg = kbase + ((size_t)b * LK + nt * BN) * DD;

  const int tid = threadIdx.x;
  const int lane = tid & 63;
  const int w = tid >> 6;        // 0..7
  const int wr = w >> 1;         // 0..3 : rows wr*32 + [0,32)
  const int wc = w & 1;          // 0..1 : cols wc*64 + [0,64)
  const int frow = lane & 15;
  const int kgrp = lane >> 4;    // 0..3

  // staging map: thread t -> row t>>2 (0..127), 8-f16 chunk t&3
  const int rowS = tid >> 2;
  const int chS = tid & 3;
  const float* pA = Ag + (size_t)rowS * DD + chS * 8;
  const float* pB = Bg + (size_t)rowS * DD + chS * 8;
  const int sidx = lidx(rowS, chS);   // per-thread constant store index

  float ssqA = 0.f, ssqB = 0.f;
  f32x4 acc[2][4] = {};

  auto LOADS = [&](int it, float4& a0, float4& a1, float4& b0, float4& b1) {
    const int koff = it * BK;    // compile-time after unroll -> imm offsets
    a0 = *(const float4*)(pA + koff);
    a1 = *(const float4*)(pA + koff + 4);
    b0 = *(const float4*)(pB + koff);
    b1 = *(const float4*)(pB + koff + 4);
  };
  auto STORE = [&](int bsel, float4 a0, float4 a1, float4 b0, float4 b1) {
    ssqA += a0.x * a0.x + a0.y * a0.y + a0.z * a0.z + a0.w * a0.w +
            a1.x * a1.x + a1.y * a1.y + a1.z * a1.z + a1.w * a1.w;
    ssqB += b0.x * b0.x + b0.y * b0.y + b0.z * b0.z + b0.w * b0.w +
            b1.x * b1.x + b1.y * b1.y + b1.z * b1.z + b1.w * b1.w;
    *(f16x8*)&As[bsel][sidx] = cvt8(a0, a1);
    *(f16x8*)&Bs[bsel][sidx] = cvt8(b0, b1);
  };
  auto COMPUTE = [&](int bsel) {
    __builtin_amdgcn_s_setprio(1);
    f16x8 af[2], bf[4];
    #pragma unroll
    for (int m = 0; m < 2; ++m)
      af[m] = *(const f16x8*)&As[bsel][lidx(wr * 32 + m * 16 + frow, kgrp)];
    #pragma unroll
    for (int n = 0; n < 4; ++n)
      bf[n] = *(const f16x8*)&Bs[bsel][lidx(wc * 64 + n * 16 + frow, kgrp)];
    #pragma unroll
    for (int m = 0; m < 2; ++m)
      #pragma unroll
      for (int n = 0; n < 4; ++n)
        acc[m][n] = __builtin_amdgcn_mfma_f32_16x16x32_f16(af[m], bf[n], acc[m][n], 0, 0, 0);
    __builtin_amdgcn_s_setprio(0);
  };

  {
    float4 a0, a1, b0, b1;
    LOADS(0, a0, a1, b0, b1);
    STORE(0, a0, a1, b0, b1);
  }
  __syncthreads();

  #pragma unroll
  for (int it = 0; it < KITERS - 1; ++it) {
    float4 a0, a1, b0, b1;
    LOADS(it + 1, a0, a1, b0, b1);   // imm-offset loads, issue early
    __builtin_amdgcn_sched_barrier(0);
    COMPUTE(it & 1);
    STORE((it & 1) ^ 1, a0, a1, b0, b1);
    __syncthreads();
  }
  COMPUTE(1);                // tile 31 (buf 1)

  // ---- epilogue: norms, column scales, row-max ----
  ssqA += __shfl_xor(ssqA, 1); ssqA += __shfl_xor(ssqA, 2);
  ssqB += __shfl_xor(ssqB, 1); ssqB += __shfl_xor(ssqB, 2);

  // aux arrays aliased onto As[0] (2048 floats avail; need 512);
  // final COMPUTE read As[1]/Bs[1] only.
  float* const aux = reinterpret_cast<float*>(&As[0][0]);
  float* const csc = aux;             // [BN]  (1/|k|)*mask
  float* const invA_s = aux + BN;     // [BM]  1/|q|
  float* const rmax = aux + BN + BM;  // [BM][2]

  if (chS == 0) {
    invA_s[rowS] = 1.0f / fmaxf(sqrtf(ssqA), EPSN);
    const int key = nt * BN + rowS;
    csc[rowS] = (mbase[(size_t)b * LK + key] ? 1.0f : 0.0f) /
                fmaxf(sqrtf(ssqB), EPSN);
  }
  __syncthreads();

  float vmax[2][4];
  #pragma unroll
  for (int m = 0; m < 2; ++m)
    #pragma unroll
    for (int r = 0; r < 4; ++r) vmax[m][r] = -INFINITY;
  #pragma unroll
  for (int n = 0; n < 4; ++n) {
    const float s = csc[wc * 64 + n * 16 + frow];
    #pragma unroll
    for (int m = 0; m < 2; ++m)
      #pragma unroll
      for (int r = 0; r < 4; ++r)
        vmax[m][r] = fmaxf(vmax[m][r], acc[m][n][r] * s);
  }
  #pragma unroll
  for (int off = 1; off < 16; off <<= 1)
    #pragma unroll
    for (int m = 0; m < 2; ++m)
      #pragma unroll
      for (int r = 0; r < 4; ++r)
        vmax[m][r] = fmaxf(vmax[m][r], __shfl_xor(vmax[m][r], off));
  if ((lane & 15) == 0) {
    #pragma unroll
    for (int m = 0; m < 2; ++m)
      #pragma unroll
      for (int r = 0; r < 4; ++r)
        rmax[(wr * 32 + m * 16 + kgrp * 4 + r) * 2 + wc] = vmax[m][r];
  }
  __syncthreads();
  if (tid < BM) {
    const float v = fmaxf(rmax[tid * 2], rmax[tid * 2 + 1]) * invA_s[tid];
    part[(((size_t)kt * NB + b) * 4 + nt) * LQ + mt * BM + tid] = v;
  }
}

// ---------------- logits + softplus per batch ----------------
__global__ __launch_bounds__(256) void logits_kernel(
    const float* __restrict__ part, const int* __restrict__ qmask,
    float* __restrict__ nll) {
  int b = blockIdx.x;
  int t = threadIdx.x;  // = lq
  float mp = -INFINITY, mn = -INFINITY;
  #pragma unroll
  for (int ntile = 0; ntile < 4; ++ntile) {
    mp = fmaxf(mp, part[(((size_t)0 * NB + b) * 4 + ntile) * LQ + t]);
    mn = fmaxf(mn, part[(((size_t)1 * NB + b) * 4 + ntile) * LQ + t]);
  }
  float qm = qmask[(size_t)b * LQ + t] ? 1.0f : 0.0f;
  float p = mp * qm;  // 1/|q| already folded into part
  float n = mn * qm;
  #pragma unroll
  for (int o = 32; o; o >>= 1) { p += __shfl_down(p, o); n += __shfl_down(n, o); }
  __shared__ float sp[4], sn[4];
  int lane = t & 63, w = t >> 6;
  if (lane == 0) { sp[w] = p; sn[w] = n; }
  __syncthreads();
  if (t == 0) {
    float ps = sp[0] + sp[1] + sp[2] + sp[3];
    float ns = sn[0] + sn[1] + sn[2] + sn[3];
    float z = (ns - ps) * TEMP_INV;
    nll[b] = z > 0.0f ? z + log1pf(expf(-z)) : log1pf(expf(z));
  }
}

__global__ void finalize_kernel(const float* __restrict__ nll, float* __restrict__ out) {
  __shared__ float s[128];
  int t = threadIdx.x;
  s[t] = nll[t];
  __syncthreads();
  #pragma unroll
  for (int o = 64; o; o >>= 1) {
    if (t < o) s[t] += s[t + o];
    __syncthreads();
  }
  if (t == 0) out[0] = s[0] * (1.0f / 128.0f);
}

extern "C" void kernel_launch(void* const* d_in, const int* in_sizes, int n_in,
                              void* d_out, int out_size, void* d_ws, size_t ws_size,
                              hipStream_t stream) {
  const float* q = (const float*)d_in[0];
  const float* pk = (const float*)d_in[1];
  const float* nk = (const float*)d_in[2];
  const int* qm = (const int*)d_in[3];
  const int* pm = (const int*)d_in[4];
  const int* nm = (const int*)d_in[5];

  float* ws = (float*)d_ws;
  float* part = ws;                // 262144 floats: [kt][b][nt][lq]
  float* nll = part + 262144;      // 128 floats

  maxsim_kernel<<<2048, 512, 0, stream>>>(q, pk, nk, pm, nm, part);
  logits_kernel<<<NB, 256, 0, stream>>>(part, qm, nll);
  finalize_kernel<<<1, 128, 0, stream>>>(nll, (float*)d_out);
}